// Round 25
// baseline (564.495 us; speedup 1.0000x reference)
//
#include <hip/hip_runtime.h>
#include <cfloat>

#define NEG_SLOPE 0.2f

// ---------------- CSR build ----------------
__global__ __launch_bounds__(256) void count_kernel(const int* __restrict__ dst,
                                                    int* __restrict__ counts, int E) {
    int e = blockIdx.x * 256 + threadIdx.x;
    if (e < E) atomicAdd(&counts[dst[e]], 1);
}

// ---- hierarchical scan: 1024 elements per block ----
__global__ __launch_bounds__(256) void scan_bsums_kernel(const int* __restrict__ counts,
                                                         int* __restrict__ bsums, int N) {
    int t = threadIdx.x;
    int base = blockIdx.x * 1024 + t * 4;
    int s = 0;
    #pragma unroll
    for (int i = 0; i < 4; ++i) { int idx = base + i; if (idx < N) s += counts[idx]; }
    #pragma unroll
    for (int d = 1; d < 64; d <<= 1) s += __shfl_xor(s, d);
    __shared__ int ws[4];
    if ((t & 63) == 0) ws[t >> 6] = s;
    __syncthreads();
    if (t == 0) bsums[blockIdx.x] = ws[0] + ws[1] + ws[2] + ws[3];
}

__global__ __launch_bounds__(64) void scan_bscan_kernel(int* __restrict__ bsums, int NB) {
    int t = threadIdx.x;
    int v = (t < NB) ? bsums[t] : 0;
    int x = v;
    #pragma unroll
    for (int d = 1; d < 64; d <<= 1) {
        int y = __shfl_up(x, d);
        if (t >= d) x += y;
    }
    if (t < NB) bsums[t] = x - v;   // exclusive
}

__global__ __launch_bounds__(256) void scan_final_kernel(const int* __restrict__ counts,
                                                         const int* __restrict__ bsums,
                                                         int* __restrict__ offs, int N) {
    int t = threadIdx.x, lane = t & 63, w = t >> 6;
    int base = blockIdx.x * 1024 + t * 4;
    int v[4]; int s = 0;
    #pragma unroll
    for (int i = 0; i < 4; ++i) { int idx = base + i; v[i] = (idx < N) ? counts[idx] : 0; s += v[i]; }
    int x = s;
    #pragma unroll
    for (int d = 1; d < 64; d <<= 1) {
        int y = __shfl_up(x, d);
        if (lane >= d) x += y;
    }
    __shared__ int wtot[4];
    if (lane == 63) wtot[w] = x;
    __syncthreads();
    int wexc = 0;
    for (int i = 0; i < w; ++i) wexc += wtot[i];
    int run = (x - s) + wexc + bsums[blockIdx.x];
    #pragma unroll
    for (int i = 0; i < 4; ++i) {
        int idx = base + i;
        run += v[i];
        if (idx < N) offs[idx + 1] = run;
    }
    if (blockIdx.x == 0 && t == 0) offs[0] = 0;
}

// 8 edges per thread: 8 independent {read, atomic, write} chains -> 8x MLP
__global__ __launch_bounds__(256) void scatter_kernel(
    const int* __restrict__ src, const int* __restrict__ dst,
    const int* __restrict__ offs, int* __restrict__ cursor,
    int4* __restrict__ csr, int E) {
    int base = (blockIdx.x * 256 + threadIdx.x) * 8;
    if (base >= E) return;
    int n = E - base; if (n > 8) n = 8;
    int s0[8], d0[8], p0[8];
    #pragma unroll
    for (int i = 0; i < 8; ++i) {
        if (i < n) { s0[i] = src[base + i]; d0[i] = dst[base + i]; }
    }
    #pragma unroll
    for (int i = 0; i < 8; ++i) {
        if (i < n) p0[i] = offs[d0[i]] + atomicAdd(&cursor[d0[i]], 1);
    }
    #pragma unroll
    for (int i = 0; i < 8; ++i) {
        if (i < n) csr[p0[i]] = make_int4(s0[i], d0[i], base + i, 0);
    }
}

// canonical order: sort each dst-segment by eid; also emits csr_src (fused extract)
__global__ __launch_bounds__(256) void sort_segments_kernel(
    int4* __restrict__ csr, int* __restrict__ csr_src,
    const int* __restrict__ offs, int N)
{
    int t = threadIdx.x;
    int lane = t & 63;
    int node = blockIdx.x * 4 + (t >> 6);
    if (node >= N) return;
    int off = offs[node];
    int deg = offs[node + 1] - off;
    if (deg <= 0) return;
    if (deg == 1) {
        if (lane == 0) csr_src[off] = csr[off].x;
        return;
    }
    if (deg <= 64) {
        int key = 0x7FFFFFFF; int4 kv = make_int4(0, 0, 0, 0);
        if (lane < deg) { kv = csr[off + lane]; key = kv.z; }
        int rank = 0;
        #pragma unroll
        for (int i = 0; i < 64; ++i) {
            int ki = __shfl(key, i);
            if (ki < key) rank++;            // eids unique -> permutation
        }
        if (lane < deg) {
            csr[off + rank] = kv;
            csr_src[off + rank] = kv.x;
        }
    } else if (lane == 0) {
        for (int a = 1; a < deg; ++a) {
            int4 kv = csr[off + a];
            int b = a - 1;
            while (b >= 0 && csr[off + b].z > kv.z) {
                csr[off + b + 1] = csr[off + b];
                b--;
            }
            csr[off + b + 1] = kv;
        }
        for (int a = 0; a < deg; ++a) csr_src[off + a] = csr[off + a].x;
    }
}

// ---------------- per-layer kernels ----------------
// node_gemm v4: 64-row tile; 4 rows per lane share each W read.
#define XSTRIDE 68
__global__ __launch_bounds__(256) void node_gemm_kernel(
    const float* __restrict__ hin,
    const float* __restrict__ Wl, const float* __restrict__ bl,
    const float* __restrict__ Wr, const float* __restrict__ br,
    float* __restrict__ xl, float* __restrict__ xr, int nrows)
{
    __shared__ float sWl[4096];
    __shared__ float sWr[4096];
    __shared__ float sX[64 * XSTRIDE];
    int t = threadIdx.x;
    {
        float4* dl = (float4*)sWl; const float4* sl = (const float4*)Wl;
        float4* dr = (float4*)sWr; const float4* sr = (const float4*)Wr;
        for (int i = t; i < 1024; i += 256) { dl[i] = sl[i]; dr[i] = sr[i]; }
    }
    int row0 = blockIdx.x * 64;
    for (int i = t; i < 1024; i += 256) {
        int rr = i >> 4;
        int cc = (i & 15) << 2;
        int row = row0 + rr;
        float4 v = make_float4(0.f, 0.f, 0.f, 0.f);
        if (row < nrows) v = *(const float4*)(hin + (size_t)row * 64 + cc);
        *(float4*)(&sX[rr * XSTRIDE + cc]) = v;
    }
    __syncthreads();

    int lane = t & 63;
    int w = t >> 6;
    int rs = lane >> 4;          // row slot 0..3
    int c4 = lane & 15;          // column quad
    int rbase = w * 16 + rs * 4; // 4 consecutive rows per lane

    float4 al0 = {0,0,0,0}, al1 = {0,0,0,0}, al2 = {0,0,0,0}, al3 = {0,0,0,0};
    float4 ar0 = {0,0,0,0}, ar1 = {0,0,0,0}, ar2 = {0,0,0,0}, ar3 = {0,0,0,0};
    const float* x0p = &sX[(rbase + 0) * XSTRIDE];
    const float* x1p = &sX[(rbase + 1) * XSTRIDE];
    const float* x2p = &sX[(rbase + 2) * XSTRIDE];
    const float* x3p = &sX[(rbase + 3) * XSTRIDE];

    #pragma unroll 4
    for (int k = 0; k < 64; ++k) {
        float4 wl4 = *(const float4*)(&sWl[k * 64 + c4 * 4]);
        float4 wr4 = *(const float4*)(&sWr[k * 64 + c4 * 4]);
        float xk0 = x0p[k], xk1 = x1p[k], xk2 = x2p[k], xk3 = x3p[k];
        al0.x += xk0 * wl4.x; al0.y += xk0 * wl4.y; al0.z += xk0 * wl4.z; al0.w += xk0 * wl4.w;
        al1.x += xk1 * wl4.x; al1.y += xk1 * wl4.y; al1.z += xk1 * wl4.z; al1.w += xk1 * wl4.w;
        al2.x += xk2 * wl4.x; al2.y += xk2 * wl4.y; al2.z += xk2 * wl4.z; al2.w += xk2 * wl4.w;
        al3.x += xk3 * wl4.x; al3.y += xk3 * wl4.y; al3.z += xk3 * wl4.z; al3.w += xk3 * wl4.w;
        ar0.x += xk0 * wr4.x; ar0.y += xk0 * wr4.y; ar0.z += xk0 * wr4.z; ar0.w += xk0 * wr4.w;
        ar1.x += xk1 * wr4.x; ar1.y += xk1 * wr4.y; ar1.z += xk1 * wr4.z; ar1.w += xk1 * wr4.w;
        ar2.x += xk2 * wr4.x; ar2.y += xk2 * wr4.y; ar2.z += xk2 * wr4.z; ar2.w += xk2 * wr4.w;
        ar3.x += xk3 * wr4.x; ar3.y += xk3 * wr4.y; ar3.z += xk3 * wr4.z; ar3.w += xk3 * wr4.w;
    }

    float4 bl4 = *(const float4*)(bl + c4 * 4);
    float4 br4 = *(const float4*)(br + c4 * 4);
    #pragma unroll
    for (int r = 0; r < 4; ++r) {
        int row = row0 + rbase + r;
        if (row >= nrows) break;
        float4 av = (r == 0) ? al0 : (r == 1) ? al1 : (r == 2) ? al2 : al3;
        float4 bv = (r == 0) ? ar0 : (r == 1) ? ar1 : (r == 2) ? ar2 : ar3;
        float4 ol, orr;
        ol.x = av.x + bl4.x; ol.y = av.y + bl4.y; ol.z = av.z + bl4.z; ol.w = av.w + bl4.w;
        orr.x = bv.x + br4.x; orr.y = bv.y + br4.y; orr.z = bv.z + br4.z; orr.w = bv.w + br4.w;
        *(float4*)(xl + (size_t)row * 64 + c4 * 4) = ol;
        *(float4*)(xr + (size_t)row * 64 + c4 * 4) = orr;
    }
}

// one thread per (CSR position, head) — 36 VGPR; min 8 waves/EU requested
__global__ __launch_bounds__(256, 8) void edge_score_kernel(
    const float* __restrict__ xl, const float* __restrict__ xr,
    const float* __restrict__ ea,
    const int4* __restrict__ csr,
    const float* __restrict__ We, const float* __restrict__ att,
    float* __restrict__ score_csr, int E)
{
    __shared__ float sWe[1024];   // 16 x 64
    __shared__ float sAtt[64];    // 4 x 16
    int t = threadIdx.x;
    for (int i = t; i < 1024; i += 256) sWe[i] = We[i];
    if (t < 64) sAtt[t] = att[t];
    __syncthreads();
    int gid = blockIdx.x * 256 + t;
    int pos = gid >> 2, h = gid & 3;
    if (pos >= E) return;
    int4 se = csr[pos];
    int s = se.x, d = se.y;
    const float4* eap = (const float4*)(ea + (size_t)se.z * 16);
    float4 a0 = eap[0], a1 = eap[1], a2 = eap[2], a3 = eap[3];
    float av[16] = {a0.x, a0.y, a0.z, a0.w, a1.x, a1.y, a1.z, a1.w,
                    a2.x, a2.y, a2.z, a2.w, a3.x, a3.y, a3.z, a3.w};
    const float4* xls = (const float4*)(xl + (size_t)s * 64 + h * 16);
    const float4* xrd = (const float4*)(xr + (size_t)d * 64 + h * 16);
    float4 vl0 = xls[0], vl1 = xls[1], vl2 = xls[2], vl3 = xls[3];
    float4 vr0 = xrd[0], vr1 = xrd[1], vr2 = xrd[2], vr3 = xrd[3];

    float4 ef0 = {0.f,0.f,0.f,0.f}, ef1 = {0.f,0.f,0.f,0.f};
    float4 ef2 = {0.f,0.f,0.f,0.f}, ef3 = {0.f,0.f,0.f,0.f};
    #pragma unroll
    for (int k = 0; k < 16; ++k) {
        float a = av[k];
        const float4* w4 = (const float4*)(&sWe[k * 64 + h * 16]);
        float4 w0 = w4[0], w1 = w4[1], w2 = w4[2], w3 = w4[3];
        ef0.x += a * w0.x; ef0.y += a * w0.y; ef0.z += a * w0.z; ef0.w += a * w0.w;
        ef1.x += a * w1.x; ef1.y += a * w1.y; ef1.z += a * w1.z; ef1.w += a * w1.w;
        ef2.x += a * w2.x; ef2.y += a * w2.y; ef2.z += a * w2.z; ef2.w += a * w2.w;
        ef3.x += a * w3.x; ef3.y += a * w3.y; ef3.z += a * w3.z; ef3.w += a * w3.w;
    }

    const float4* at4 = (const float4*)(&sAtt[h * 16]);
    float4 at0 = at4[0], at1 = at4[1], at2 = at4[2], at3 = at4[3];

    float sc0 = 0.f, sc1 = 0.f, sc2 = 0.f, sc3 = 0.f;
    {
        float m0 = vl0.x + vr0.x + ef0.x; m0 = (m0 >= 0.f) ? m0 : NEG_SLOPE * m0;
        float m1 = vl0.y + vr0.y + ef0.y; m1 = (m1 >= 0.f) ? m1 : NEG_SLOPE * m1;
        float m2 = vl0.z + vr0.z + ef0.z; m2 = (m2 >= 0.f) ? m2 : NEG_SLOPE * m2;
        float m3 = vl0.w + vr0.w + ef0.w; m3 = (m3 >= 0.f) ? m3 : NEG_SLOPE * m3;
        sc0 += m0 * at0.x; sc1 += m1 * at0.y; sc2 += m2 * at0.z; sc3 += m3 * at0.w;
    }
    {
        float m0 = vl1.x + vr1.x + ef1.x; m0 = (m0 >= 0.f) ? m0 : NEG_SLOPE * m0;
        float m1 = vl1.y + vr1.y + ef1.y; m1 = (m1 >= 0.f) ? m1 : NEG_SLOPE * m1;
        float m2 = vl1.z + vr1.z + ef1.z; m2 = (m2 >= 0.f) ? m2 : NEG_SLOPE * m2;
        float m3 = vl1.w + vr1.w + ef1.w; m3 = (m3 >= 0.f) ? m3 : NEG_SLOPE * m3;
        sc0 += m0 * at1.x; sc1 += m1 * at1.y; sc2 += m2 * at1.z; sc3 += m3 * at1.w;
    }
    {
        float m0 = vl2.x + vr2.x + ef2.x; m0 = (m0 >= 0.f) ? m0 : NEG_SLOPE * m0;
        float m1 = vl2.y + vr2.y + ef2.y; m1 = (m1 >= 0.f) ? m1 : NEG_SLOPE * m1;
        float m2 = vl2.z + vr2.z + ef2.z; m2 = (m2 >= 0.f) ? m2 : NEG_SLOPE * m2;
        float m3 = vl2.w + vr2.w + ef2.w; m3 = (m3 >= 0.f) ? m3 : NEG_SLOPE * m3;
        sc0 += m0 * at2.x; sc1 += m1 * at2.y; sc2 += m2 * at2.z; sc3 += m3 * at2.w;
    }
    {
        float m0 = vl3.x + vr3.x + ef3.x; m0 = (m0 >= 0.f) ? m0 : NEG_SLOPE * m0;
        float m1 = vl3.y + vr3.y + ef3.y; m1 = (m1 >= 0.f) ? m1 : NEG_SLOPE * m1;
        float m2 = vl3.z + vr3.z + ef3.z; m2 = (m2 >= 0.f) ? m2 : NEG_SLOPE * m2;
        float m3 = vl3.w + vr3.w + ef3.w; m3 = (m3 >= 0.f) ? m3 : NEG_SLOPE * m3;
        sc0 += m0 * at3.x; sc1 += m1 * at3.y; sc2 += m2 * at3.z; sc3 += m3 * at3.w;
    }
    score_csr[gid] = (sc0 + sc1) + (sc2 + sc3);
}

// one WAVE per node; lane=(eg 0..3, k 0..15); single-pass online softmax.
__global__ __launch_bounds__(256, 8) void node_pass_kernel(
    const float* __restrict__ score_csr, const float* __restrict__ xl,
    const int* __restrict__ csr_src,
    const int* __restrict__ offs, const float* __restrict__ bias,
    float* __restrict__ hout, int N)
{
    int t = threadIdx.x;
    int lane = t & 63;
    int node = blockIdx.x * 4 + (t >> 6);
    if (node >= N) return;
    int eg = lane >> 4;          // edge slot
    int k  = lane & 15;          // channel quad; head = k>>2
    int h  = k >> 2;
    int off = offs[node];
    int deg = offs[node + 1] - off;

    if (deg == 0) {
        if (eg == 0) {
            float4 b = *(const float4*)(bias + k * 4);
            float4 o;
            o.x = fmaxf(b.x, 0.f); o.y = fmaxf(b.y, 0.f);
            o.z = fmaxf(b.z, 0.f); o.w = fmaxf(b.w, 0.f);
            *(float4*)(hout + (size_t)node * 64 + k * 4) = o;
        }
        return;
    }

    float m = -FLT_MAX, sSum = 0.f;
    float4 acc = {0.f, 0.f, 0.f, 0.f};
    for (int j0 = 0; j0 < deg; j0 += 4) {
        int j = j0 + eg;
        if (j < deg) {
            int pos = off + j;
            int s = csr_src[pos];
            float sc = score_csr[(size_t)pos * 4 + h];
            float4 v = *(const float4*)(xl + (size_t)s * 64 + k * 4);
            float nm = fmaxf(m, sc);
            float cs = __expf(m - nm);     // 0 on first edge
            float p  = __expf(sc - nm);
            sSum = sSum * cs + p;
            acc.x = acc.x * cs + p * v.x; acc.y = acc.y * cs + p * v.y;
            acc.z = acc.z * cs + p * v.z; acc.w = acc.w * cs + p * v.w;
            m = nm;
        }
    }

    // merge 4 slot states (fixed xor order -> deterministic)
    #pragma unroll
    for (int st = 16; st < 64; st <<= 1) {
        float mo = __shfl_xor(m, st);
        float so = __shfl_xor(sSum, st);
        float4 vo;
        vo.x = __shfl_xor(acc.x, st); vo.y = __shfl_xor(acc.y, st);
        vo.z = __shfl_xor(acc.z, st); vo.w = __shfl_xor(acc.w, st);
        float nm = fmaxf(m, mo);
        float cs = __expf(m - nm);
        float co = __expf(mo - nm);
        sSum = sSum * cs + so * co;
        acc.x = acc.x * cs + vo.x * co; acc.y = acc.y * cs + vo.y * co;
        acc.z = acc.z * cs + vo.z * co; acc.w = acc.w * cs + vo.w * co;
        m = nm;
    }

    if (eg == 0) {
        float inv = 1.f / sSum;
        float4 b = *(const float4*)(bias + k * 4);
        float4 o;
        o.x = fmaxf(acc.x * inv + b.x, 0.f);
        o.y = fmaxf(acc.y * inv + b.y, 0.f);
        o.z = fmaxf(acc.z * inv + b.z, 0.f);
        o.w = fmaxf(acc.w * inv + b.w, 0.f);
        *(float4*)(hout + (size_t)node * 64 + k * 4) = o;
    }
}

extern "C" void kernel_launch(void* const* d_in, const int* in_sizes, int n_in,
                              void* d_out, int out_size, void* d_ws, size_t ws_size,
                              hipStream_t stream) {
    const float* x    = (const float*)d_in[0];
    const int*   eidx = (const int*)d_in[1];
    const float* ea   = (const float*)d_in[2];
    const float* Wl   = (const float*)d_in[3];
    const float* bl   = (const float*)d_in[4];
    const float* Wr   = (const float*)d_in[5];
    const float* br   = (const float*)d_in[6];
    const float* We   = (const float*)d_in[7];
    const float* att  = (const float*)d_in[8];
    const float* bias = (const float*)d_in[9];
    float* out = (float*)d_out;

    const int N = in_sizes[0] / 64;
    const int E = in_sizes[1] / 2;
    const int* src = eidx;
    const int* dst = eidx + E;

    float* ws = (float*)d_ws;
    float* xl      = ws;                               // N*64
    float* xr      = xl + (size_t)N * 64;              // N*64
    float* score   = xr + (size_t)N * 64;              // E*4
    float* h_tmp   = score + (size_t)E * 4;            // N*64
    int* counts    = (int*)(h_tmp + (size_t)N * 64);   // N
    int* cursor    = counts + N;                       // N (contiguous with counts)
    int* offs      = cursor + N;                       // N+1
    int* bsums     = offs + N + 1;                     // 64
    int* csr_src   = bsums + 64;                       // E
    uintptr_t p    = (uintptr_t)(csr_src + E);
    p = (p + 15) & ~(uintptr_t)15;
    int4* csr      = (int4*)p;                         // E int4 (16B aligned)

    dim3 blk(256);
    int g_e    = (E + 255) / 256;
    int g_e8   = (E + 2047) / 2048;
    int g_eh   = (E * 4 + 255) / 256;
    int g_gemm = (N + 63) / 64;
    int g_node = (N + 3) / 4;
    int NB     = (N + 1023) / 1024;   // 49 for N=50000 (<= 64)

    // CSR over dst, canonical eid order (edge_index is layer-invariant)
    hipMemsetAsync(counts, 0, 2 * (size_t)N * sizeof(int), stream);  // counts + cursor
    count_kernel<<<g_e, blk, 0, stream>>>(dst, counts, E);
    scan_bsums_kernel<<<NB, blk, 0, stream>>>(counts, bsums, N);
    scan_bscan_kernel<<<1, 64, 0, stream>>>(bsums, NB);
    scan_final_kernel<<<NB, blk, 0, stream>>>(counts, bsums, offs, N);
    scatter_kernel<<<g_e8, blk, 0, stream>>>(src, dst, offs, cursor, csr, E);
    sort_segments_kernel<<<g_node, blk, 0, stream>>>(csr, csr_src, offs, N);

    const float* hin = x;
    for (int l = 0; l < 3; ++l) {
        float* hout = (l == 2) ? out : h_tmp;
        node_gemm_kernel<<<g_gemm, blk, 0, stream>>>(hin, Wl + (size_t)l * 4096, bl + l * 64,
                                                     Wr + (size_t)l * 4096, br + l * 64, xl, xr, N);
        edge_score_kernel<<<g_eh, blk, 0, stream>>>(xl, xr, ea, csr,
                                                    We + (size_t)l * 1024, att + l * 64,
                                                    score, E);
        node_pass_kernel<<<g_node, blk, 0, stream>>>(score, xl, csr_src, offs,
                                                     bias + l * 64, hout, N);
        hin = hout;
    }
}

// Round 26
// 464.697 us; speedup vs baseline: 1.2148x; 1.2148x over previous
//
#include <hip/hip_runtime.h>
#include <cfloat>

#define NEG_SLOPE 0.2f

// ---------------- CSR build ----------------
__global__ __launch_bounds__(256) void count_kernel(const int* __restrict__ dst,
                                                    int* __restrict__ counts, int E) {
    int e = blockIdx.x * 256 + threadIdx.x;
    if (e < E) atomicAdd(&counts[dst[e]], 1);
}

// ---- hierarchical scan: 1024 elements per block ----
__global__ __launch_bounds__(256) void scan_bsums_kernel(const int* __restrict__ counts,
                                                         int* __restrict__ bsums, int N) {
    int t = threadIdx.x;
    int base = blockIdx.x * 1024 + t * 4;
    int s = 0;
    #pragma unroll
    for (int i = 0; i < 4; ++i) { int idx = base + i; if (idx < N) s += counts[idx]; }
    #pragma unroll
    for (int d = 1; d < 64; d <<= 1) s += __shfl_xor(s, d);
    __shared__ int ws[4];
    if ((t & 63) == 0) ws[t >> 6] = s;
    __syncthreads();
    if (t == 0) bsums[blockIdx.x] = ws[0] + ws[1] + ws[2] + ws[3];
}

__global__ __launch_bounds__(64) void scan_bscan_kernel(int* __restrict__ bsums, int NB) {
    int t = threadIdx.x;
    int v = (t < NB) ? bsums[t] : 0;
    int x = v;
    #pragma unroll
    for (int d = 1; d < 64; d <<= 1) {
        int y = __shfl_up(x, d);
        if (t >= d) x += y;
    }
    if (t < NB) bsums[t] = x - v;   // exclusive
}

__global__ __launch_bounds__(256) void scan_final_kernel(const int* __restrict__ counts,
                                                         const int* __restrict__ bsums,
                                                         int* __restrict__ offs, int N) {
    int t = threadIdx.x, lane = t & 63, w = t >> 6;
    int base = blockIdx.x * 1024 + t * 4;
    int v[4]; int s = 0;
    #pragma unroll
    for (int i = 0; i < 4; ++i) { int idx = base + i; v[i] = (idx < N) ? counts[idx] : 0; s += v[i]; }
    int x = s;
    #pragma unroll
    for (int d = 1; d < 64; d <<= 1) {
        int y = __shfl_up(x, d);
        if (lane >= d) x += y;
    }
    __shared__ int wtot[4];
    if (lane == 63) wtot[w] = x;
    __syncthreads();
    int wexc = 0;
    for (int i = 0; i < w; ++i) wexc += wtot[i];
    int run = (x - s) + wexc + bsums[blockIdx.x];
    #pragma unroll
    for (int i = 0; i < 4; ++i) {
        int idx = base + i;
        run += v[i];
        if (idx < N) offs[idx + 1] = run;
    }
    if (blockIdx.x == 0 && t == 0) offs[0] = 0;
}

// 8 edges per thread: 8 independent {read, atomic, write} chains -> 8x MLP
__global__ __launch_bounds__(256) void scatter_kernel(
    const int* __restrict__ src, const int* __restrict__ dst,
    const int* __restrict__ offs, int* __restrict__ cursor,
    int4* __restrict__ csr, int E) {
    int base = (blockIdx.x * 256 + threadIdx.x) * 8;
    if (base >= E) return;
    int n = E - base; if (n > 8) n = 8;
    int s0[8], d0[8], p0[8];
    #pragma unroll
    for (int i = 0; i < 8; ++i) {
        if (i < n) { s0[i] = src[base + i]; d0[i] = dst[base + i]; }
    }
    #pragma unroll
    for (int i = 0; i < 8; ++i) {
        if (i < n) p0[i] = offs[d0[i]] + atomicAdd(&cursor[d0[i]], 1);
    }
    #pragma unroll
    for (int i = 0; i < 8; ++i) {
        if (i < n) csr[p0[i]] = make_int4(s0[i], d0[i], base + i, 0);
    }
}

// canonical order: sort each dst-segment by eid; also emits csr_src (fused extract)
__global__ __launch_bounds__(256) void sort_segments_kernel(
    int4* __restrict__ csr, int* __restrict__ csr_src,
    const int* __restrict__ offs, int N)
{
    int t = threadIdx.x;
    int lane = t & 63;
    int node = blockIdx.x * 4 + (t >> 6);
    if (node >= N) return;
    int off = offs[node];
    int deg = offs[node + 1] - off;
    if (deg <= 0) return;
    if (deg == 1) {
        if (lane == 0) csr_src[off] = csr[off].x;
        return;
    }
    if (deg <= 64) {
        int key = 0x7FFFFFFF; int4 kv = make_int4(0, 0, 0, 0);
        if (lane < deg) { kv = csr[off + lane]; key = kv.z; }
        int rank = 0;
        #pragma unroll
        for (int i = 0; i < 64; ++i) {
            int ki = __shfl(key, i);
            if (ki < key) rank++;            // eids unique -> permutation
        }
        if (lane < deg) {
            csr[off + rank] = kv;
            csr_src[off + rank] = kv.x;
        }
    } else if (lane == 0) {
        for (int a = 1; a < deg; ++a) {
            int4 kv = csr[off + a];
            int b = a - 1;
            while (b >= 0 && csr[off + b].z > kv.z) {
                csr[off + b + 1] = csr[off + b];
                b--;
            }
            csr[off + b + 1] = kv;
        }
        for (int a = 0; a < deg; ++a) csr_src[off + a] = csr[off + a].x;
    }
}

// ---------------- per-layer kernels ----------------
// node_gemm v4: 64-row tile; 4 rows per lane share each W read.
#define XSTRIDE 68
__global__ __launch_bounds__(256) void node_gemm_kernel(
    const float* __restrict__ hin,
    const float* __restrict__ Wl, const float* __restrict__ bl,
    const float* __restrict__ Wr, const float* __restrict__ br,
    float* __restrict__ xl, float* __restrict__ xr, int nrows)
{
    __shared__ float sWl[4096];
    __shared__ float sWr[4096];
    __shared__ float sX[64 * XSTRIDE];
    int t = threadIdx.x;
    {
        float4* dl = (float4*)sWl; const float4* sl = (const float4*)Wl;
        float4* dr = (float4*)sWr; const float4* sr = (const float4*)Wr;
        for (int i = t; i < 1024; i += 256) { dl[i] = sl[i]; dr[i] = sr[i]; }
    }
    int row0 = blockIdx.x * 64;
    for (int i = t; i < 1024; i += 256) {
        int rr = i >> 4;
        int cc = (i & 15) << 2;
        int row = row0 + rr;
        float4 v = make_float4(0.f, 0.f, 0.f, 0.f);
        if (row < nrows) v = *(const float4*)(hin + (size_t)row * 64 + cc);
        *(float4*)(&sX[rr * XSTRIDE + cc]) = v;
    }
    __syncthreads();

    int lane = t & 63;
    int w = t >> 6;
    int rs = lane >> 4;          // row slot 0..3
    int c4 = lane & 15;          // column quad
    int rbase = w * 16 + rs * 4; // 4 consecutive rows per lane

    float4 al0 = {0,0,0,0}, al1 = {0,0,0,0}, al2 = {0,0,0,0}, al3 = {0,0,0,0};
    float4 ar0 = {0,0,0,0}, ar1 = {0,0,0,0}, ar2 = {0,0,0,0}, ar3 = {0,0,0,0};
    const float* x0p = &sX[(rbase + 0) * XSTRIDE];
    const float* x1p = &sX[(rbase + 1) * XSTRIDE];
    const float* x2p = &sX[(rbase + 2) * XSTRIDE];
    const float* x3p = &sX[(rbase + 3) * XSTRIDE];

    #pragma unroll 4
    for (int k = 0; k < 64; ++k) {
        float4 wl4 = *(const float4*)(&sWl[k * 64 + c4 * 4]);
        float4 wr4 = *(const float4*)(&sWr[k * 64 + c4 * 4]);
        float xk0 = x0p[k], xk1 = x1p[k], xk2 = x2p[k], xk3 = x3p[k];
        al0.x += xk0 * wl4.x; al0.y += xk0 * wl4.y; al0.z += xk0 * wl4.z; al0.w += xk0 * wl4.w;
        al1.x += xk1 * wl4.x; al1.y += xk1 * wl4.y; al1.z += xk1 * wl4.z; al1.w += xk1 * wl4.w;
        al2.x += xk2 * wl4.x; al2.y += xk2 * wl4.y; al2.z += xk2 * wl4.z; al2.w += xk2 * wl4.w;
        al3.x += xk3 * wl4.x; al3.y += xk3 * wl4.y; al3.z += xk3 * wl4.z; al3.w += xk3 * wl4.w;
        ar0.x += xk0 * wr4.x; ar0.y += xk0 * wr4.y; ar0.z += xk0 * wr4.z; ar0.w += xk0 * wr4.w;
        ar1.x += xk1 * wr4.x; ar1.y += xk1 * wr4.y; ar1.z += xk1 * wr4.z; ar1.w += xk1 * wr4.w;
        ar2.x += xk2 * wr4.x; ar2.y += xk2 * wr4.y; ar2.z += xk2 * wr4.z; ar2.w += xk2 * wr4.w;
        ar3.x += xk3 * wr4.x; ar3.y += xk3 * wr4.y; ar3.z += xk3 * wr4.z; ar3.w += xk3 * wr4.w;
    }

    float4 bl4 = *(const float4*)(bl + c4 * 4);
    float4 br4 = *(const float4*)(br + c4 * 4);
    #pragma unroll
    for (int r = 0; r < 4; ++r) {
        int row = row0 + rbase + r;
        if (row >= nrows) break;
        float4 av = (r == 0) ? al0 : (r == 1) ? al1 : (r == 2) ? al2 : al3;
        float4 bv = (r == 0) ? ar0 : (r == 1) ? ar1 : (r == 2) ? ar2 : ar3;
        float4 ol, orr;
        ol.x = av.x + bl4.x; ol.y = av.y + bl4.y; ol.z = av.z + bl4.z; ol.w = av.w + bl4.w;
        orr.x = bv.x + br4.x; orr.y = bv.y + br4.y; orr.z = bv.z + br4.z; orr.w = bv.w + br4.w;
        *(float4*)(xl + (size_t)row * 64 + c4 * 4) = ol;
        *(float4*)(xr + (size_t)row * 64 + c4 * 4) = orr;
    }
}

// one thread per (CSR position, head) — 36 VGPR, natural allocation (no min-wave bound:
// forcing 8 waves/EU spilled to scratch, +300MB HBM traffic, 63->114us. R25 lesson.)
__global__ __launch_bounds__(256) void edge_score_kernel(
    const float* __restrict__ xl, const float* __restrict__ xr,
    const float* __restrict__ ea,
    const int4* __restrict__ csr,
    const float* __restrict__ We, const float* __restrict__ att,
    float* __restrict__ score_csr, int E)
{
    __shared__ float sWe[1024];   // 16 x 64
    __shared__ float sAtt[64];    // 4 x 16
    int t = threadIdx.x;
    for (int i = t; i < 1024; i += 256) sWe[i] = We[i];
    if (t < 64) sAtt[t] = att[t];
    __syncthreads();
    int gid = blockIdx.x * 256 + t;
    int pos = gid >> 2, h = gid & 3;
    if (pos >= E) return;
    int4 se = csr[pos];
    int s = se.x, d = se.y;
    const float4* eap = (const float4*)(ea + (size_t)se.z * 16);
    float4 a0 = eap[0], a1 = eap[1], a2 = eap[2], a3 = eap[3];
    float av[16] = {a0.x, a0.y, a0.z, a0.w, a1.x, a1.y, a1.z, a1.w,
                    a2.x, a2.y, a2.z, a2.w, a3.x, a3.y, a3.z, a3.w};
    const float4* xls = (const float4*)(xl + (size_t)s * 64 + h * 16);
    const float4* xrd = (const float4*)(xr + (size_t)d * 64 + h * 16);
    float4 vl0 = xls[0], vl1 = xls[1], vl2 = xls[2], vl3 = xls[3];
    float4 vr0 = xrd[0], vr1 = xrd[1], vr2 = xrd[2], vr3 = xrd[3];

    float4 ef0 = {0.f,0.f,0.f,0.f}, ef1 = {0.f,0.f,0.f,0.f};
    float4 ef2 = {0.f,0.f,0.f,0.f}, ef3 = {0.f,0.f,0.f,0.f};
    #pragma unroll
    for (int k = 0; k < 16; ++k) {
        float a = av[k];
        const float4* w4 = (const float4*)(&sWe[k * 64 + h * 16]);
        float4 w0 = w4[0], w1 = w4[1], w2 = w4[2], w3 = w4[3];
        ef0.x += a * w0.x; ef0.y += a * w0.y; ef0.z += a * w0.z; ef0.w += a * w0.w;
        ef1.x += a * w1.x; ef1.y += a * w1.y; ef1.z += a * w1.z; ef1.w += a * w1.w;
        ef2.x += a * w2.x; ef2.y += a * w2.y; ef2.z += a * w2.z; ef2.w += a * w2.w;
        ef3.x += a * w3.x; ef3.y += a * w3.y; ef3.z += a * w3.z; ef3.w += a * w3.w;
    }

    const float4* at4 = (const float4*)(&sAtt[h * 16]);
    float4 at0 = at4[0], at1 = at4[1], at2 = at4[2], at3 = at4[3];

    float sc0 = 0.f, sc1 = 0.f, sc2 = 0.f, sc3 = 0.f;
    {
        float m0 = vl0.x + vr0.x + ef0.x; m0 = (m0 >= 0.f) ? m0 : NEG_SLOPE * m0;
        float m1 = vl0.y + vr0.y + ef0.y; m1 = (m1 >= 0.f) ? m1 : NEG_SLOPE * m1;
        float m2 = vl0.z + vr0.z + ef0.z; m2 = (m2 >= 0.f) ? m2 : NEG_SLOPE * m2;
        float m3 = vl0.w + vr0.w + ef0.w; m3 = (m3 >= 0.f) ? m3 : NEG_SLOPE * m3;
        sc0 += m0 * at0.x; sc1 += m1 * at0.y; sc2 += m2 * at0.z; sc3 += m3 * at0.w;
    }
    {
        float m0 = vl1.x + vr1.x + ef1.x; m0 = (m0 >= 0.f) ? m0 : NEG_SLOPE * m0;
        float m1 = vl1.y + vr1.y + ef1.y; m1 = (m1 >= 0.f) ? m1 : NEG_SLOPE * m1;
        float m2 = vl1.z + vr1.z + ef1.z; m2 = (m2 >= 0.f) ? m2 : NEG_SLOPE * m2;
        float m3 = vl1.w + vr1.w + ef1.w; m3 = (m3 >= 0.f) ? m3 : NEG_SLOPE * m3;
        sc0 += m0 * at1.x; sc1 += m1 * at1.y; sc2 += m2 * at1.z; sc3 += m3 * at1.w;
    }
    {
        float m0 = vl2.x + vr2.x + ef2.x; m0 = (m0 >= 0.f) ? m0 : NEG_SLOPE * m0;
        float m1 = vl2.y + vr2.y + ef2.y; m1 = (m1 >= 0.f) ? m1 : NEG_SLOPE * m1;
        float m2 = vl2.z + vr2.z + ef2.z; m2 = (m2 >= 0.f) ? m2 : NEG_SLOPE * m2;
        float m3 = vl2.w + vr2.w + ef2.w; m3 = (m3 >= 0.f) ? m3 : NEG_SLOPE * m3;
        sc0 += m0 * at2.x; sc1 += m1 * at2.y; sc2 += m2 * at2.z; sc3 += m3 * at2.w;
    }
    {
        float m0 = vl3.x + vr3.x + ef3.x; m0 = (m0 >= 0.f) ? m0 : NEG_SLOPE * m0;
        float m1 = vl3.y + vr3.y + ef3.y; m1 = (m1 >= 0.f) ? m1 : NEG_SLOPE * m1;
        float m2 = vl3.z + vr3.z + ef3.z; m2 = (m2 >= 0.f) ? m2 : NEG_SLOPE * m2;
        float m3 = vl3.w + vr3.w + ef3.w; m3 = (m3 >= 0.f) ? m3 : NEG_SLOPE * m3;
        sc0 += m0 * at3.x; sc1 += m1 * at3.y; sc2 += m2 * at3.z; sc3 += m3 * at3.w;
    }
    score_csr[gid] = (sc0 + sc1) + (sc2 + sc3);
}

// one WAVE per node; lane=(eg 0..3, k 0..15); single-pass online softmax.
__global__ __launch_bounds__(256) void node_pass_kernel(
    const float* __restrict__ score_csr, const float* __restrict__ xl,
    const int* __restrict__ csr_src,
    const int* __restrict__ offs, const float* __restrict__ bias,
    float* __restrict__ hout, int N)
{
    int t = threadIdx.x;
    int lane = t & 63;
    int node = blockIdx.x * 4 + (t >> 6);
    if (node >= N) return;
    int eg = lane >> 4;          // edge slot
    int k  = lane & 15;          // channel quad; head = k>>2
    int h  = k >> 2;
    int off = offs[node];
    int deg = offs[node + 1] - off;

    if (deg == 0) {
        if (eg == 0) {
            float4 b = *(const float4*)(bias + k * 4);
            float4 o;
            o.x = fmaxf(b.x, 0.f); o.y = fmaxf(b.y, 0.f);
            o.z = fmaxf(b.z, 0.f); o.w = fmaxf(b.w, 0.f);
            *(float4*)(hout + (size_t)node * 64 + k * 4) = o;
        }
        return;
    }

    float m = -FLT_MAX, sSum = 0.f;
    float4 acc = {0.f, 0.f, 0.f, 0.f};
    for (int j0 = 0; j0 < deg; j0 += 4) {
        int j = j0 + eg;
        if (j < deg) {
            int pos = off + j;
            int s = csr_src[pos];
            float sc = score_csr[(size_t)pos * 4 + h];
            float4 v = *(const float4*)(xl + (size_t)s * 64 + k * 4);
            float nm = fmaxf(m, sc);
            float cs = __expf(m - nm);     // 0 on first edge
            float p  = __expf(sc - nm);
            sSum = sSum * cs + p;
            acc.x = acc.x * cs + p * v.x; acc.y = acc.y * cs + p * v.y;
            acc.z = acc.z * cs + p * v.z; acc.w = acc.w * cs + p * v.w;
            m = nm;
        }
    }

    // merge 4 slot states (fixed xor order -> deterministic)
    #pragma unroll
    for (int st = 16; st < 64; st <<= 1) {
        float mo = __shfl_xor(m, st);
        float so = __shfl_xor(sSum, st);
        float4 vo;
        vo.x = __shfl_xor(acc.x, st); vo.y = __shfl_xor(acc.y, st);
        vo.z = __shfl_xor(acc.z, st); vo.w = __shfl_xor(acc.w, st);
        float nm = fmaxf(m, mo);
        float cs = __expf(m - nm);
        float co = __expf(mo - nm);
        sSum = sSum * cs + so * co;
        acc.x = acc.x * cs + vo.x * co; acc.y = acc.y * cs + vo.y * co;
        acc.z = acc.z * cs + vo.z * co; acc.w = acc.w * cs + vo.w * co;
        m = nm;
    }

    if (eg == 0) {
        float inv = 1.f / sSum;
        float4 b = *(const float4*)(bias + k * 4);
        float4 o;
        o.x = fmaxf(acc.x * inv + b.x, 0.f);
        o.y = fmaxf(acc.y * inv + b.y, 0.f);
        o.z = fmaxf(acc.z * inv + b.z, 0.f);
        o.w = fmaxf(acc.w * inv + b.w, 0.f);
        *(float4*)(hout + (size_t)node * 64 + k * 4) = o;
    }
}

extern "C" void kernel_launch(void* const* d_in, const int* in_sizes, int n_in,
                              void* d_out, int out_size, void* d_ws, size_t ws_size,
                              hipStream_t stream) {
    const float* x    = (const float*)d_in[0];
    const int*   eidx = (const int*)d_in[1];
    const float* ea   = (const float*)d_in[2];
    const float* Wl   = (const float*)d_in[3];
    const float* bl   = (const float*)d_in[4];
    const float* Wr   = (const float*)d_in[5];
    const float* br   = (const float*)d_in[6];
    const float* We   = (const float*)d_in[7];
    const float* att  = (const float*)d_in[8];
    const float* bias = (const float*)d_in[9];
    float* out = (float*)d_out;

    const int N = in_sizes[0] / 64;
    const int E = in_sizes[1] / 2;
    const int* src = eidx;
    const int* dst = eidx + E;

    float* ws = (float*)d_ws;
    float* xl      = ws;                               // N*64
    float* xr      = xl + (size_t)N * 64;              // N*64
    float* score   = xr + (size_t)N * 64;              // E*4
    float* h_tmp   = score + (size_t)E * 4;            // N*64
    int* counts    = (int*)(h_tmp + (size_t)N * 64);   // N
    int* cursor    = counts + N;                       // N (contiguous with counts)
    int* offs      = cursor + N;                       // N+1
    int* bsums     = offs + N + 1;                     // 64
    int* csr_src   = bsums + 64;                       // E
    uintptr_t p    = (uintptr_t)(csr_src + E);
    p = (p + 15) & ~(uintptr_t)15;
    int4* csr      = (int4*)p;                         // E int4 (16B aligned)

    dim3 blk(256);
    int g_e    = (E + 255) / 256;
    int g_e8   = (E + 2047) / 2048;
    int g_eh   = (E * 4 + 255) / 256;
    int g_gemm = (N + 63) / 64;
    int g_node = (N + 3) / 4;
    int NB     = (N + 1023) / 1024;   // 49 for N=50000 (<= 64)

    // CSR over dst, canonical eid order (edge_index is layer-invariant)
    hipMemsetAsync(counts, 0, 2 * (size_t)N * sizeof(int), stream);  // counts + cursor
    count_kernel<<<g_e, blk, 0, stream>>>(dst, counts, E);
    scan_bsums_kernel<<<NB, blk, 0, stream>>>(counts, bsums, N);
    scan_bscan_kernel<<<1, 64, 0, stream>>>(bsums, NB);
    scan_final_kernel<<<NB, blk, 0, stream>>>(counts, bsums, offs, N);
    scatter_kernel<<<g_e8, blk, 0, stream>>>(src, dst, offs, cursor, csr, E);
    sort_segments_kernel<<<g_node, blk, 0, stream>>>(csr, csr_src, offs, N);

    const float* hin = x;
    for (int l = 0; l < 3; ++l) {
        float* hout = (l == 2) ? out : h_tmp;
        node_gemm_kernel<<<g_gemm, blk, 0, stream>>>(hin, Wl + (size_t)l * 4096, bl + l * 64,
                                                     Wr + (size_t)l * 4096, br + l * 64, xl, xr, N);
        edge_score_kernel<<<g_eh, blk, 0, stream>>>(xl, xr, ea, csr,
                                                    We + (size_t)l * 1024, att + l * 64,
                                                    score, E);
        node_pass_kernel<<<g_node, blk, 0, stream>>>(score, xl, csr_src, offs,
                                                     bias + l * 64, hout, N);
        hin = hout;
    }
}